// Round 9
// baseline (153.558 us; speedup 1.0000x reference)
//
#include <hip/hip_runtime.h>

// LIF integrate-fire-reset scan over T.
// inputs: [B=32, T=2048, N=1024] f32; thresh: [N] f32; out: [B, T, N] f32.
//
// R9 structure: each LANE owns 4 ADJACENT chains (float4). Wave w covers
// batch b = w>>2, columns (w&3)*256 + [0..255]; lane l handles columns
// 4l..4l+3 of that quarter-row. Every load/store is global_*_dwordx4 and the
// wave's 64 lanes cover 1 KB CONTIGUOUS per timestep (vs 256 B scattered in
// the scalar R7 kernel) -> copy-benchmark-like DRAM request granularity,
// with ZERO LDS / shuffles (chains stay lane-local).
//
// 128 waves on 128 CUs; per-CU demand ~44 GB/s << per-CU L1 path (~130).
// Latency hiding: in-place circular register pipeline, depth D=32 timesteps:
//   use buf[i] -> refill buf[i] from t+D+i. Wait depth at use = 31 younger
//   loads + 32 stores = 63 = max expressible vmcnt (fits exactly).
// In flight: 32 KB loads/wave x 128 waves = 4 MB > ~2.5 MB BW*latency.

typedef float f32x4 __attribute__((ext_vector_type(4)));

constexpr int T_STEPS = 2048;
constexpr int N_COLS  = 1024;
constexpr int D       = 32;   // pipeline depth in timesteps (T_STEPS % D == 0)

__global__ __launch_bounds__(64, 1)
void lif_scan_kernel(const float* __restrict__ x,
                     const float* __restrict__ thresh,
                     float* __restrict__ out)
{
    const int w    = blockIdx.x;                      // 0..127 (one wave/block)
    const int b    = w >> 2;                          // batch
    const int col  = ((w & 3) << 8) | (threadIdx.x << 2);  // first of 4 columns

    const f32x4 thr = *(const f32x4*)&thresh[col];

    const size_t base = (size_t)b * T_STEPS * N_COLS + col;
    const float* __restrict__ p = x   + base;
    float*       __restrict__ q = out + base;

    f32x4 buf[D];   // static indexing only -> stays in VGPRs (~128)

    // prologue: prime the pipeline
#pragma unroll
    for (int i = 0; i < D; ++i)
        buf[i] = __builtin_nontemporal_load((const f32x4*)(p + (size_t)i * N_COLS));

    f32x4 acc = {0.0f, 0.0f, 0.0f, 0.0f};

#define LIF_STEP(V, O)                                                     \
    acc.x += (V).x; (O).x = (acc.x > thr.x) ? acc.x : 0.0f; acc.x -= (O).x; \
    acc.y += (V).y; (O).y = (acc.y > thr.y) ? acc.y : 0.0f; acc.y -= (O).y; \
    acc.z += (V).z; (O).z = (acc.z > thr.z) ? acc.z : 0.0f; acc.z -= (O).z; \
    acc.w += (V).w; (O).w = (acc.w > thr.w) ? acc.w : 0.0f; acc.w -= (O).w;

    // steady state: consume slot i, immediately refill it D timesteps ahead
    for (int t0 = 0; t0 < T_STEPS - D; t0 += D) {
#pragma unroll
        for (int i = 0; i < D; ++i) {
            const f32x4 v = buf[i];
            buf[i] = __builtin_nontemporal_load(
                (const f32x4*)(p + (size_t)(t0 + D + i) * N_COLS));
            f32x4 o;
            LIF_STEP(v, o)
            __builtin_nontemporal_store(o, (f32x4*)(q + (size_t)(t0 + i) * N_COLS));
        }
    }

    // epilogue: drain the last D timesteps (no further loads)
#pragma unroll
    for (int i = 0; i < D; ++i) {
        const f32x4 v = buf[i];
        f32x4 o;
        LIF_STEP(v, o)
        __builtin_nontemporal_store(o, (f32x4*)(q + (size_t)(T_STEPS - D + i) * N_COLS));
    }

#undef LIF_STEP
}

extern "C" void kernel_launch(void* const* d_in, const int* in_sizes, int n_in,
                              void* d_out, int out_size, void* d_ws, size_t ws_size,
                              hipStream_t stream)
{
    const float* x      = (const float*)d_in[0];
    const float* thresh = (const float*)d_in[1];
    float*       out    = (float*)d_out;

    const int chains = in_sizes[0] / T_STEPS;        // B * N = 32768
    const int grid   = chains / (64 * 4);            // 128 single-wave blocks
    (void)out_size; (void)d_ws; (void)ws_size; (void)n_in;

    hipLaunchKernelGGL(lif_scan_kernel, dim3(grid), dim3(64), 0, stream,
                       x, thresh, out);
}

// Round 10
// 111.703 us; speedup vs baseline: 1.3747x; 1.3747x over previous
//
#include <hip/hip_runtime.h>

// LIF integrate-fire-reset scan over T.
// inputs: [B=32, T=2048, N=1024] f32; thresh: [N] f32; out: [B, T, N] f32.
//
// R10 = R7 (scalar chain/lane, in-place circular register pipeline D=32)
// + XCD-AWARE WORK REMAP (T1). R7 assigned consecutive blockIdx ->
// consecutive 256 B slabs of one batch-row, and dispatch round-robins
// blockIdx across the 8 XCDs -> each XCD's L2->HBM stream was 64 scattered
// 4KB-strided slab streams, interleaved 8-ways at the controllers (no DRAM
// row locality). Remap so XCD x owns batches 4x..4x+3 COMPLETELY: the 16
// slabs covering one batch-row share an L2, so each XCD emits ~4 sequential
// region streams instead of 64 scattered ones.
//
//   i = blockIdx (0..511); xcd = i&7; j = i>>3 (0..63)
//   b = 4*xcd + (j>>4);  n-slab = (j&15)*64
//
// Rationale: R7/R8/R9 established we're DRAM-pattern-bound, not
// concurrency-bound (per-wave byte rate invariant to op size/depth; real
// HBM traffic only ~3.8 TB/s at 105.7 us due to L3 hits).

constexpr int T_STEPS = 2048;
constexpr int N_COLS  = 1024;
constexpr int D       = 32;   // pipeline depth (T_STEPS % D == 0)

__global__ __launch_bounds__(64, 1)
void lif_scan_kernel(const float* __restrict__ x,
                     const float* __restrict__ thresh,
                     float* __restrict__ out)
{
    // XCD-aware decomposition of blockIdx -> (batch, column-slab)
    const int i   = blockIdx.x;            // 0..511, i&7 ~ XCD id
    const int xcd = i & 7;
    const int j   = i >> 3;                // 0..63 within XCD
    const int b   = (xcd << 2) | (j >> 4); // 4 batches per XCD
    const int n   = ((j & 15) << 6) | threadIdx.x;  // column slab + lane

    const float thr = thresh[n];

    const size_t base = (size_t)b * T_STEPS * N_COLS + n;
    const float* __restrict__ p = x   + base;
    float*       __restrict__ q = out + base;

    float buf[D];

    // prologue: prime the pipeline
#pragma unroll
    for (int i2 = 0; i2 < D; ++i2)
        buf[i2] = __builtin_nontemporal_load(&p[(size_t)i2 * N_COLS]);

    float acc = 0.0f;

    // steady state: per element, consume slot i then refill it D ahead.
    for (int t0 = 0; t0 < T_STEPS - D; t0 += D) {
#pragma unroll
        for (int i2 = 0; i2 < D; ++i2) {
            const float v = buf[i2];
            buf[i2] = __builtin_nontemporal_load(&p[(size_t)(t0 + D + i2) * N_COLS]);
            acc += v;
            const float o = (acc > thr) ? acc : 0.0f;
            acc -= o;   // reset fired neuron to 0
            __builtin_nontemporal_store(o, &q[(size_t)(t0 + i2) * N_COLS]);
        }
    }

    // epilogue: drain the last D elements (no further loads)
#pragma unroll
    for (int i2 = 0; i2 < D; ++i2) {
        acc += buf[i2];
        const float o = (acc > thr) ? acc : 0.0f;
        acc -= o;
        __builtin_nontemporal_store(o, &q[(size_t)(T_STEPS - D + i2) * N_COLS]);
    }
}

extern "C" void kernel_launch(void* const* d_in, const int* in_sizes, int n_in,
                              void* d_out, int out_size, void* d_ws, size_t ws_size,
                              hipStream_t stream)
{
    const float* x      = (const float*)d_in[0];
    const float* thresh = (const float*)d_in[1];
    float*       out    = (float*)d_out;

    const int total = in_sizes[0] / T_STEPS;   // B * N chains = 32768
    (void)out_size; (void)d_ws; (void)ws_size; (void)n_in;

    const int block = 64;
    const int grid  = (total + block - 1) / block;   // 512 blocks

    hipLaunchKernelGGL(lif_scan_kernel, dim3(grid), dim3(block), 0, stream,
                       x, thresh, out);
}

// Round 11
// 81.962 us; speedup vs baseline: 1.8735x; 1.3629x over previous
//
#include <hip/hip_runtime.h>

// LIF integrate-fire-reset scan over T.
// inputs: [B=32, T=2048, N=1024] f32; thresh: [N] f32; out: [B, T, N] f32.
//
// R11 = R7 (best: scalar chain/lane, in-place circular register pipeline,
// D=32, natural block order) with ONE change: loads are PLAIN (L2/L3
// caching) instead of nontemporal; stores remain nontemporal.
//
// Why: the per-wave VMEM pipeline is HW-capped at 63 outstanding ops
// (6-bit vmcnt) = 16 KB/wave = 8 MB chip-wide — every structure tried
// (R5/R7/R8/R9) sits on the same in-flight*latency curve, implying a
// ~1.6 us loaded round-trip. The 268 MB input is ~exactly L3-sized and is
// re-read on every timed replay; nt loads (no-allocate) were denying L3
// residency (R9: FETCH = half input even so). Caching loads should make
// the input ~L3-resident across replays, cutting the latency term the
// fixed in-flight bytes must cover. nt stores keep the 268 MB output
// stream from evicting the input.

constexpr int T_STEPS = 2048;
constexpr int N_COLS  = 1024;
constexpr int D       = 32;   // pipeline depth (T_STEPS % D == 0)

__global__ __launch_bounds__(64, 1)
void lif_scan_kernel(const float* __restrict__ x,
                     const float* __restrict__ thresh,
                     float* __restrict__ out)
{
    const int gid = blockIdx.x * blockDim.x + threadIdx.x;   // 0 .. B*N-1
    const int b   = gid >> 10;          // / N_COLS
    const int n   = gid & (N_COLS - 1); // % N_COLS

    const float thr = thresh[n];

    const size_t base = (size_t)b * T_STEPS * N_COLS + n;
    const float* __restrict__ p = x   + base;
    float*       __restrict__ q = out + base;

    float buf[D];

    // prologue: prime the pipeline (plain cached loads)
#pragma unroll
    for (int i = 0; i < D; ++i)
        buf[i] = p[(size_t)i * N_COLS];

    float acc = 0.0f;

    // steady state: per element, consume slot i then refill it D ahead.
    for (int t0 = 0; t0 < T_STEPS - D; t0 += D) {
#pragma unroll
        for (int i = 0; i < D; ++i) {
            const float v = buf[i];
            buf[i] = p[(size_t)(t0 + D + i) * N_COLS];
            acc += v;
            const float o = (acc > thr) ? acc : 0.0f;
            acc -= o;   // reset fired neuron to 0
            __builtin_nontemporal_store(o, &q[(size_t)(t0 + i) * N_COLS]);
        }
    }

    // epilogue: drain the last D elements (no further loads)
#pragma unroll
    for (int i = 0; i < D; ++i) {
        acc += buf[i];
        const float o = (acc > thr) ? acc : 0.0f;
        acc -= o;
        __builtin_nontemporal_store(o, &q[(size_t)(T_STEPS - D + i) * N_COLS]);
    }
}

extern "C" void kernel_launch(void* const* d_in, const int* in_sizes, int n_in,
                              void* d_out, int out_size, void* d_ws, size_t ws_size,
                              hipStream_t stream)
{
    const float* x      = (const float*)d_in[0];
    const float* thresh = (const float*)d_in[1];
    float*       out    = (float*)d_out;

    const int total = in_sizes[0] / T_STEPS;   // B * N chains
    (void)out_size; (void)d_ws; (void)ws_size; (void)n_in;

    const int block = 64;
    const int grid  = (total + block - 1) / block;   // 512 blocks

    hipLaunchKernelGGL(lif_scan_kernel, dim3(grid), dim3(block), 0, stream,
                       x, thresh, out);
}